// Round 21
// baseline (106.526 us; speedup 1.0000x reference)
//
#include <hip/hip_runtime.h>
#include <hip/hip_bf16.h>
#include <hip/hip_fp16.h>
#include <cstdint>

#define NV 64000      // B*N nodes
#define DD 64         // hidden dim
#define FF 3          // input features
#define NE 1000000    // edges
#define BB 32         // batch (graphs)
#define SS 50         // timesteps
#define NN 2000       // nodes per graph
#define KB 1000       // coarse buckets (dst >> 6), 64 dsts each (round-21: reverted to 1000)
#define CAP 1536      // records per bucket region (mean 1000, +17 sigma)
#define NBLKA 500     // partition blocks (round-21: 250->500, clean single-variable test)
#define EPB (NE / NBLKA)  // 2000 edges per partition block
#define TMB 750       // tmean blocks (750*256 == NV*FF)
#define INVALID 0xFFFFFFFFu
#define RPW 16        // rows per wave in trans2pool
#define NWAVES (NV / RPW)   // 4000
#define WPG (NN / RPW)      // 125 partials per graph
#define RST 20        // rT row stride (words): %4==0 keeps b128 alignment

// ---------------------------------------------------------------------------
// FAT kernel: blocks [0,NBLKA) partition edges (latency/atomic bound);
// blocks [NBLKA,NBLKA+TMB) stream the temporal mean (HBM-bound) -> overlap.
// int64-vs-int32 detection inlined per part-block; gcur pre-zeroed by memset.
// ---------------------------------------------------------------------------
__global__ __launch_bounds__(256) void part_tmean_kernel(const int* __restrict__ ei32,
                                                         int* __restrict__ gcur,
                                                         unsigned* __restrict__ parts,
                                                         const float* __restrict__ x,
                                                         float* __restrict__ p0) {
    int t = threadIdx.x;
    if (blockIdx.x >= NBLKA) {
        int tid = (blockIdx.x - NBLKA) * 256 + t;   // < NV*FF
        int nf = tid % (NN * FF);
        int b  = tid / (NN * FF);
        const float* xp = x + (size_t)b * SS * NN * FF + nf;
        float acc = 0.f;
        #pragma unroll
        for (int s = 0; s < SS; ++s) acc += xp[(size_t)s * NN * FF];
        p0[tid] = acc * (1.0f / SS);
        return;
    }
    __shared__ unsigned recs[EPB];   // 8 KB
    __shared__ int cnt[KB];          // 4 KB
    __shared__ int cur[KB];          // 4 KB
    __shared__ int nz;
    if (t == 0) nz = 0;
    for (int i = t; i < KB; i += 256) cnt[i] = 0;
    __syncthreads();
    int local = 0;
    for (int k = t; k < 4096; k += 256) local |= (ei32[2 * k + 1] != 0);
    if (local) atomicOr(&nz, 1);
    __syncthreads();
    const int is64 = (nz == 0);
    const long long* ei64 = (const long long*)ei32;
    int e0 = blockIdx.x * EPB;
    for (int i = t; i < EPB; i += 256) {
        int e = e0 + i;
        int s, d;
        if (is64) { s = (int)ei64[e]; d = (int)ei64[NE + e]; }
        else      { s = ei32[e];      d = ei32[NE + e]; }
        bool ok = (unsigned)s < NV && (unsigned)d < NV;
        recs[i] = ok ? (((unsigned)s << 16) | (unsigned)d) : INVALID;
        if (ok) atomicAdd(&cnt[d >> 6], 1);
    }
    __syncthreads();
    for (int b = t; b < KB; b += 256) {
        int c = cnt[b];
        cur[b] = (c > 0) ? atomicAdd(&gcur[b], c) : 0;
    }
    __syncthreads();
    for (int i = t; i < EPB; i += 256) {
        unsigned r = recs[i];
        if (r != INVALID) {
            int d = (int)(r & 0xFFFFu);
            int b = d >> 6;
            int pos = atomicAdd(&cur[b], 1);
            if (pos < CAP)
                parts[(size_t)b * CAP + pos] = ((r >> 16) << 6) | (unsigned)(d & 63);
        }
    }
}

// ---------------------------------------------------------------------------
// Per-bucket LDS counting sort -> beg/end + dinv; sorted src ids in place.
// Tail: scale this bucket's 64 p0 rows by dinv.
// ---------------------------------------------------------------------------
__global__ __launch_bounds__(256) void bsort_kernel(unsigned* __restrict__ parts,
                                                    const int* __restrict__ gcur,
                                                    int* __restrict__ beg,
                                                    int* __restrict__ end,
                                                    float* __restrict__ dinv,
                                                    float* __restrict__ p0) {
    __shared__ unsigned recs[CAP];
    __shared__ int srt[CAP];
    __shared__ int cnt64[64];
    __shared__ int pref[64];
    __shared__ int cur[64];
    int b = blockIdx.x, t = threadIdx.x;
    int cnt = min(gcur[b], CAP);
    unsigned* p = parts + (size_t)b * CAP;
    if (t < 64) cnt64[t] = 0;
    __syncthreads();
    for (int i = t; i < cnt; i += 256) {
        unsigned r = p[i];
        recs[i] = r;
        atomicAdd(&cnt64[r & 63u], 1);
    }
    __syncthreads();
    if (t < 64) pref[t] = cnt64[t];
    __syncthreads();
    #pragma unroll
    for (int off = 1; off < 64; off <<= 1) {
        int v = (t < 64 && t >= off) ? pref[t - off] : 0;
        __syncthreads();
        if (t < 64) pref[t] += v;
        __syncthreads();
    }
    if (t < 64) {
        int ex = pref[t] - cnt64[t];
        cur[t] = ex;
        int node = (b << 6) + t;
        beg[node] = b * CAP + ex;
        end[node] = b * CAP + ex + cnt64[t];
        dinv[node] = rsqrtf((float)(cnt64[t] + 1));
    }
    __syncthreads();
    for (int i = t; i < cnt; i += 256) {
        unsigned r = recs[i];
        int pos = atomicAdd(&cur[r & 63u], 1);
        srt[pos] = (int)(r >> 6);
    }
    __syncthreads();
    for (int i = t; i < cnt; i += 256) p[i] = (unsigned)srt[i];
    for (int i = t; i < 64 * FF; i += 256) {
        float dv = rsqrtf((float)(cnt64[i / FF] + 1));
        p0[(size_t)b * 64 * FF + i] *= dv;
    }
}

// ---------------------------------------------------------------------------
// FUSED layer-1 aggregation + transform. Block = 256 nodes.
// Phase 1: per-thread 3-dim gather (p0 L2-resident) -> LDS float4 {q0,dinv}.
// Phase 2: coalesced p1h production (W1 coefficients hoisted per thread).
// ---------------------------------------------------------------------------
__global__ __launch_bounds__(256) void agg3trans_kernel(const int* __restrict__ beg,
                                                        const int* __restrict__ end,
                                                        const unsigned* __restrict__ srcs,
                                                        const float* __restrict__ p0,
                                                        const float* __restrict__ dinv,
                                                        const float* __restrict__ W1,
                                                        const float* __restrict__ b1,
                                                        __half2* __restrict__ p1h) {
    __shared__ float4 q4s[256];
    int t = threadIdx.x;
    int node = blockIdx.x * 256 + t;
    int e = beg[node], en = end[node];
    float a0 = p0[node * 3 + 0], a1 = p0[node * 3 + 1], a2 = p0[node * 3 + 2];
    for (; e + 2 <= en; e += 2) {
        int s0 = srcs[e] * 3, s1 = srcs[e + 1] * 3;
        float u0 = p0[s0], u1 = p0[s0 + 1], u2 = p0[s0 + 2];
        float w0 = p0[s1], w1 = p0[s1 + 1], w2 = p0[s1 + 2];
        a0 += u0 + w0; a1 += u1 + w1; a2 += u2 + w2;
    }
    for (; e < en; ++e) {
        int s = srcs[e] * 3;
        a0 += p0[s]; a1 += p0[s + 1]; a2 += p0[s + 2];
    }
    q4s[t] = make_float4(a0, a1, a2, dinv[node]);
    __syncthreads();
    int j = t & 31;
    int d0 = 2 * j, d1 = d0 + 1;
    float w00 = W1[d0], w10 = W1[64 + d0], w20 = W1[128 + d0], bb0 = b1[d0];
    float w01 = W1[d1], w11 = W1[64 + d1], w21 = W1[128 + d1], bb1 = b1[d1];
    size_t base = (size_t)blockIdx.x * 256 * 32;
    #pragma unroll 8
    for (int i = 0; i < 32; ++i) {
        int idx = t + 256 * i;
        float4 q = q4s[idx >> 5];
        float h0 = fmaf(q.w, fmaf(q.x, w00, fmaf(q.y, w10, q.z * w20)), bb0);
        float h1 = fmaf(q.w, fmaf(q.x, w01, fmaf(q.y, w11, q.z * w21)), bb1);
        p1h[base + idx] = __floats2half2_rn(q.w * fmaxf(h0, 0.f), q.w * fmaxf(h1, 0.f));
    }
}

// ---------------------------------------------------------------------------
// 64-dim aggregation, fp16 in / fp16 out: row = 128 B = 8 lanes x 16 B.
// 8-lane group grp takes edges e0+grp+8k (2-deep); fp32 accumulate;
// butterfly (^8,^16,^32); grp 0 packs to half2 and stores 16 B.
// ---------------------------------------------------------------------------
__global__ __launch_bounds__(256) void agg64_kernel(const int* __restrict__ beg,
                                                    const int* __restrict__ end,
                                                    const unsigned* __restrict__ srcs,
                                                    const __half2* __restrict__ g,
                                                    __half2* __restrict__ q1h) {
    int lane = threadIdx.x & 63;
    int node = (blockIdx.x * blockDim.x + threadIdx.x) >> 6;
    if (node >= NV) return;
    int grp = lane >> 3, sub = lane & 7;
    const uint4* base = (const uint4*)g;   // 8 uint4 per node row
    float a0 = 0.f, a1 = 0.f, a2 = 0.f, a3 = 0.f;
    float a4 = 0.f, a5 = 0.f, a6 = 0.f, a7 = 0.f;
#define UNPACK_ADD(v) do { float2 f_;                                         \
        f_ = __half22float2(*(const __half2*)&(v).x); a0 += f_.x; a1 += f_.y; \
        f_ = __half22float2(*(const __half2*)&(v).y); a2 += f_.x; a3 += f_.y; \
        f_ = __half22float2(*(const __half2*)&(v).z); a4 += f_.x; a5 += f_.y; \
        f_ = __half22float2(*(const __half2*)&(v).w); a6 += f_.x; a7 += f_.y; } while (0)
    if (grp == 0) {
        uint4 v = base[((size_t)node << 3) + sub];   // self loop
        UNPACK_ADD(v);
    }
    int e = beg[node] + grp, en = end[node];
    for (; e + 8 < en; e += 16) {
        uint4 v0 = base[((size_t)srcs[e] << 3) + sub];
        uint4 v1 = base[((size_t)srcs[e + 8] << 3) + sub];
        UNPACK_ADD(v0);
        UNPACK_ADD(v1);
    }
    if (e < en) {
        uint4 v = base[((size_t)srcs[e] << 3) + sub];
        UNPACK_ADD(v);
    }
#undef UNPACK_ADD
    #pragma unroll
    for (int m = 8; m <= 32; m <<= 1) {
        a0 += __shfl_xor(a0, m); a1 += __shfl_xor(a1, m);
        a2 += __shfl_xor(a2, m); a3 += __shfl_xor(a3, m);
        a4 += __shfl_xor(a4, m); a5 += __shfl_xor(a5, m);
        a6 += __shfl_xor(a6, m); a7 += __shfl_xor(a7, m);
    }
    if (grp == 0) {
        uint4 o;
        *(__half2*)&o.x = __floats2half2_rn(a0, a1);
        *(__half2*)&o.y = __floats2half2_rn(a2, a3);
        *(__half2*)&o.z = __floats2half2_rn(a4, a5);
        *(__half2*)&o.w = __floats2half2_rn(a6, a7);
        ((uint4*)q1h)[((size_t)node << 3) + sub] = o;
    }
}

// ---------------------------------------------------------------------------
// Fused layer-2 transform + partial pooling: 4x4 register-tiled GEMM,
// 0.125 LDS-fetch/FMA, fp16 q1 input (converted to fp32 in LDS staging).
// ---------------------------------------------------------------------------
__global__ __launch_bounds__(256) void trans2pool_kernel(const __half* __restrict__ q1h,
                                                         const float* __restrict__ dinv,
                                                         const float* __restrict__ b2,
                                                         const float* __restrict__ W2,
                                                         float* __restrict__ partials) {
    __shared__ float w2s[64 * 64];        // 16 KB, [k][d]
    __shared__ float rT[4][64 * RST];     // 20 KB, per-wave transposed rows [k][r]
    int t = threadIdx.x;
    int lane = t & 63, wvid = t >> 6;
    for (int i = t; i < 64 * 64; i += 256) w2s[i] = W2[i];

    int wid = blockIdx.x * 4 + wvid;
    int n0 = wid * RPW;
    float v[16];
    #pragma unroll
    for (int i = 0; i < 16; ++i)
        v[i] = __half2float(q1h[((size_t)(n0 + i) << 6) + lane]);
    float* rw = rT[wvid];
    #pragma unroll
    for (int r0 = 0; r0 < 16; r0 += 4)
        *(float4*)&rw[lane * RST + r0] = make_float4(v[r0], v[r0 + 1], v[r0 + 2], v[r0 + 3]);
    __syncthreads();

    int ri0 = (lane >> 4) * 4;            // row sub-tile: 0,4,8,12
    int c0 = (lane & 15) * 4;             // col sub-tile: 0..60
    float acc00 = 0.f, acc01 = 0.f, acc02 = 0.f, acc03 = 0.f;
    float acc10 = 0.f, acc11 = 0.f, acc12 = 0.f, acc13 = 0.f;
    float acc20 = 0.f, acc21 = 0.f, acc22 = 0.f, acc23 = 0.f;
    float acc30 = 0.f, acc31 = 0.f, acc32 = 0.f, acc33 = 0.f;
    #pragma unroll 2
    for (int k = 0; k < 64; ++k) {
        float4 w4 = *(const float4*)&w2s[k * 64 + c0];
        float4 r4 = *(const float4*)&rw[k * RST + ri0];
        acc00 = fmaf(r4.x, w4.x, acc00); acc01 = fmaf(r4.x, w4.y, acc01);
        acc02 = fmaf(r4.x, w4.z, acc02); acc03 = fmaf(r4.x, w4.w, acc03);
        acc10 = fmaf(r4.y, w4.x, acc10); acc11 = fmaf(r4.y, w4.y, acc11);
        acc12 = fmaf(r4.y, w4.z, acc12); acc13 = fmaf(r4.y, w4.w, acc13);
        acc20 = fmaf(r4.z, w4.x, acc20); acc21 = fmaf(r4.z, w4.y, acc21);
        acc22 = fmaf(r4.z, w4.z, acc22); acc23 = fmaf(r4.z, w4.w, acc23);
        acc30 = fmaf(r4.w, w4.x, acc30); acc31 = fmaf(r4.w, w4.y, acc31);
        acc32 = fmaf(r4.w, w4.z, acc32); acc33 = fmaf(r4.w, w4.w, acc33);
    }
    float4 bv = *(const float4*)&b2[c0];
    float d0 = dinv[n0 + ri0 + 0], d1 = dinv[n0 + ri0 + 1];
    float d2 = dinv[n0 + ri0 + 2], d3 = dinv[n0 + ri0 + 3];
    float s0 = fmaxf(fmaf(d0, acc00, bv.x), 0.f) + fmaxf(fmaf(d1, acc10, bv.x), 0.f)
             + fmaxf(fmaf(d2, acc20, bv.x), 0.f) + fmaxf(fmaf(d3, acc30, bv.x), 0.f);
    float s1 = fmaxf(fmaf(d0, acc01, bv.y), 0.f) + fmaxf(fmaf(d1, acc11, bv.y), 0.f)
             + fmaxf(fmaf(d2, acc21, bv.y), 0.f) + fmaxf(fmaf(d3, acc31, bv.y), 0.f);
    float s2 = fmaxf(fmaf(d0, acc02, bv.z), 0.f) + fmaxf(fmaf(d1, acc12, bv.z), 0.f)
             + fmaxf(fmaf(d2, acc22, bv.z), 0.f) + fmaxf(fmaf(d3, acc32, bv.z), 0.f);
    float s3 = fmaxf(fmaf(d0, acc03, bv.w), 0.f) + fmaxf(fmaf(d1, acc13, bv.w), 0.f)
             + fmaxf(fmaf(d2, acc23, bv.w), 0.f) + fmaxf(fmaf(d3, acc33, bv.w), 0.f);
    s0 += __shfl_xor(s0, 16); s1 += __shfl_xor(s1, 16);
    s2 += __shfl_xor(s2, 16); s3 += __shfl_xor(s3, 16);
    s0 += __shfl_xor(s0, 32); s1 += __shfl_xor(s1, 32);
    s2 += __shfl_xor(s2, 32); s3 += __shfl_xor(s3, 32);
    if (lane < 16)
        *(float4*)&partials[(size_t)wid * 64 + c0] = make_float4(s0, s1, s2, s3);
}

// Reduce WPG=125 partials per graph (4-way parallel); apply head.
__global__ __launch_bounds__(256) void pool_finish_kernel(const float* __restrict__ partials,
                                                          const float* __restrict__ Wh,
                                                          const float* __restrict__ bh,
                                                          float* __restrict__ out) {
    __shared__ float part[4][64];
    __shared__ float pooled[64];
    int b = blockIdx.x;
    int t = threadIdx.x;
    int d = t & 63, g = t >> 6;
    float s = 0.f;
    for (int c = g; c < WPG; c += 4)
        s += partials[((size_t)(b * WPG + c)) * 64 + d];
    part[g][d] = s;
    __syncthreads();
    if (t < 64)
        pooled[t] = (part[0][t] + part[1][t] + part[2][t] + part[3][t]) * (1.0f / NN);
    __syncthreads();
    if (t < 2) {
        float o = bh[t];
        #pragma unroll 16
        for (int k = 0; k < 64; ++k) o += pooled[k] * Wh[k * 2 + t];
        out[b * 2 + t] = o;
    }
}

extern "C" void kernel_launch(void* const* d_in, const int* in_sizes, int n_in,
                              void* d_out, int out_size, void* d_ws, size_t ws_size,
                              hipStream_t stream) {
    const float* x  = (const float*)d_in[0];
    const int*   ei = (const int*)d_in[1];
    const float* W1 = (const float*)d_in[2];
    const float* b1 = (const float*)d_in[3];
    const float* W2 = (const float*)d_in[4];
    const float* b2 = (const float*)d_in[5];
    const float* Wh = (const float*)d_in[6];
    const float* bh = (const float*)d_in[7];
    float* out = (float*)d_out;

    float* ws   = (float*)d_ws;
    float* bufA = ws;                          // NV*DD floats reserved (p1h: 8 MB)
    float* bufB = bufA + (size_t)NV * DD;      // NV*DD floats reserved (q1h: 8 MB)
    float* p0   = bufB + (size_t)NV * DD;      // NV*FF
    float* dinv = p0 + (size_t)NV * FF;        // NV
    float* partials = dinv + NV;               // NWAVES*64
    unsigned* parts = (unsigned*)(partials + (size_t)NWAVES * 64);  // KB*CAP
    int*   beg  = (int*)(parts + (size_t)KB * CAP);                 // NV
    int*   end  = beg + NV;                    // NV
    int*   gcur = end + NV;                    // KB
    __half2* p1h = (__half2*)bufA;             // NV*32 half2 (8 MB)
    __half2* q1h = (__half2*)bufB;             // NV*32 half2 (8 MB)

    // --- zero bucket cursors (async, capture-safe), then fat part+tmean ---
    hipMemsetAsync(gcur, 0, KB * sizeof(int), stream);
    part_tmean_kernel<<<NBLKA + TMB, 256, 0, stream>>>(ei, gcur, parts, x, p0);

    // --- per-bucket sort (+ dinv, + p0 scaling) ---
    bsort_kernel<<<KB, 256, 0, stream>>>(parts, gcur, beg, end, dinv, p0);

    // --- FUSED layer-1 aggregation + transform -> fp16 p1 ---
    agg3trans_kernel<<<NV / 256, 256, 0, stream>>>(beg, end, parts, p0, dinv, W1, b1, p1h);

    // --- Layer 2 aggregation (fp16 gather, fp32 accumulate, fp16 out) ---
    agg64_kernel<<<NV * 64 / 256, 256, 0, stream>>>(beg, end, parts, p1h, q1h);

    // --- Fused layer-2 transform + partial pool (4x4 register-tiled GEMM) ---
    trans2pool_kernel<<<NWAVES / 4, 256, 0, stream>>>((const __half*)q1h, dinv, b2, W2, partials);

    // --- Head ---
    pool_finish_kernel<<<BB, 256, 0, stream>>>(partials, Wh, bh, out);
}

// Round 22
// 101.023 us; speedup vs baseline: 1.0545x; 1.0545x over previous
//
#include <hip/hip_runtime.h>
#include <hip/hip_bf16.h>
#include <hip/hip_fp16.h>
#include <cstdint>

#define NV 64000      // B*N nodes
#define DD 64         // hidden dim
#define FF 3          // input features
#define NE 1000000    // edges
#define BB 32         // batch (graphs)
#define SS 50         // timesteps
#define NN 2000       // nodes per graph
#define KB 1000       // coarse buckets (dst >> 6), 64 dsts each
#define CAP 1536      // records per bucket region (mean 1000, +17 sigma)
#define NBLKA 250     // partition blocks (round-22: reverted to proven round-19 config)
#define EPB (NE / NBLKA)  // 4000 edges per partition block
#define TMB 750       // tmean blocks (750*256 == NV*FF)
#define INVALID 0xFFFFFFFFu
#define RPW 16        // rows per wave in trans2pool
#define NWAVES (NV / RPW)   // 4000
#define WPG (NN / RPW)      // 125 partials per graph
#define RST 20        // rT row stride (words): %4==0 keeps b128 alignment

// ---------------------------------------------------------------------------
// FAT kernel: blocks [0,NBLKA) partition edges (latency/atomic bound);
// blocks [NBLKA,NBLKA+TMB) stream the temporal mean (HBM-bound) -> overlap.
// int64-vs-int32 detection inlined per part-block; gcur pre-zeroed by memset.
// ---------------------------------------------------------------------------
__global__ __launch_bounds__(256) void part_tmean_kernel(const int* __restrict__ ei32,
                                                         int* __restrict__ gcur,
                                                         unsigned* __restrict__ parts,
                                                         const float* __restrict__ x,
                                                         float* __restrict__ p0) {
    int t = threadIdx.x;
    if (blockIdx.x >= NBLKA) {
        int tid = (blockIdx.x - NBLKA) * 256 + t;   // < NV*FF
        int nf = tid % (NN * FF);
        int b  = tid / (NN * FF);
        const float* xp = x + (size_t)b * SS * NN * FF + nf;
        float acc = 0.f;
        #pragma unroll
        for (int s = 0; s < SS; ++s) acc += xp[(size_t)s * NN * FF];
        p0[tid] = acc * (1.0f / SS);
        return;
    }
    __shared__ unsigned recs[EPB];   // 16 KB
    __shared__ int cnt[KB];          // 4 KB
    __shared__ int cur[KB];          // 4 KB
    __shared__ int nz;
    if (t == 0) nz = 0;
    for (int i = t; i < KB; i += 256) cnt[i] = 0;
    __syncthreads();
    int local = 0;
    for (int k = t; k < 4096; k += 256) local |= (ei32[2 * k + 1] != 0);
    if (local) atomicOr(&nz, 1);
    __syncthreads();
    const int is64 = (nz == 0);
    const long long* ei64 = (const long long*)ei32;
    int e0 = blockIdx.x * EPB;
    for (int i = t; i < EPB; i += 256) {
        int e = e0 + i;
        int s, d;
        if (is64) { s = (int)ei64[e]; d = (int)ei64[NE + e]; }
        else      { s = ei32[e];      d = ei32[NE + e]; }
        bool ok = (unsigned)s < NV && (unsigned)d < NV;
        recs[i] = ok ? (((unsigned)s << 16) | (unsigned)d) : INVALID;
        if (ok) atomicAdd(&cnt[d >> 6], 1);
    }
    __syncthreads();
    for (int b = t; b < KB; b += 256) {
        int c = cnt[b];
        cur[b] = (c > 0) ? atomicAdd(&gcur[b], c) : 0;
    }
    __syncthreads();
    for (int i = t; i < EPB; i += 256) {
        unsigned r = recs[i];
        if (r != INVALID) {
            int d = (int)(r & 0xFFFFu);
            int b = d >> 6;
            int pos = atomicAdd(&cur[b], 1);
            if (pos < CAP)
                parts[(size_t)b * CAP + pos] = ((r >> 16) << 6) | (unsigned)(d & 63);
        }
    }
}

// ---------------------------------------------------------------------------
// Per-bucket LDS counting sort -> beg/end + dinv; sorted src ids in place.
// Tail: scale this bucket's 64 p0 rows by dinv.
// ---------------------------------------------------------------------------
__global__ __launch_bounds__(256) void bsort_kernel(unsigned* __restrict__ parts,
                                                    const int* __restrict__ gcur,
                                                    int* __restrict__ beg,
                                                    int* __restrict__ end,
                                                    float* __restrict__ dinv,
                                                    float* __restrict__ p0) {
    __shared__ unsigned recs[CAP];
    __shared__ int srt[CAP];
    __shared__ int cnt64[64];
    __shared__ int pref[64];
    __shared__ int cur[64];
    int b = blockIdx.x, t = threadIdx.x;
    int cnt = min(gcur[b], CAP);
    unsigned* p = parts + (size_t)b * CAP;
    if (t < 64) cnt64[t] = 0;
    __syncthreads();
    for (int i = t; i < cnt; i += 256) {
        unsigned r = p[i];
        recs[i] = r;
        atomicAdd(&cnt64[r & 63u], 1);
    }
    __syncthreads();
    if (t < 64) pref[t] = cnt64[t];
    __syncthreads();
    #pragma unroll
    for (int off = 1; off < 64; off <<= 1) {
        int v = (t < 64 && t >= off) ? pref[t - off] : 0;
        __syncthreads();
        if (t < 64) pref[t] += v;
        __syncthreads();
    }
    if (t < 64) {
        int ex = pref[t] - cnt64[t];
        cur[t] = ex;
        int node = (b << 6) + t;
        beg[node] = b * CAP + ex;
        end[node] = b * CAP + ex + cnt64[t];
        dinv[node] = rsqrtf((float)(cnt64[t] + 1));
    }
    __syncthreads();
    for (int i = t; i < cnt; i += 256) {
        unsigned r = recs[i];
        int pos = atomicAdd(&cur[r & 63u], 1);
        srt[pos] = (int)(r >> 6);
    }
    __syncthreads();
    for (int i = t; i < cnt; i += 256) p[i] = (unsigned)srt[i];
    for (int i = t; i < 64 * FF; i += 256) {
        float dv = rsqrtf((float)(cnt64[i / FF] + 1));
        p0[(size_t)b * 64 * FF + i] *= dv;
    }
}

// ---------------------------------------------------------------------------
// FUSED layer-1 aggregation + transform. Block = 256 nodes.
// Phase 1: per-thread 3-dim gather (p0 L2-resident) -> LDS float4 {q0,dinv}.
// Phase 2: coalesced p1h production (W1 coefficients hoisted per thread).
// ---------------------------------------------------------------------------
__global__ __launch_bounds__(256) void agg3trans_kernel(const int* __restrict__ beg,
                                                        const int* __restrict__ end,
                                                        const unsigned* __restrict__ srcs,
                                                        const float* __restrict__ p0,
                                                        const float* __restrict__ dinv,
                                                        const float* __restrict__ W1,
                                                        const float* __restrict__ b1,
                                                        __half2* __restrict__ p1h) {
    __shared__ float4 q4s[256];
    int t = threadIdx.x;
    int node = blockIdx.x * 256 + t;
    int e = beg[node], en = end[node];
    float a0 = p0[node * 3 + 0], a1 = p0[node * 3 + 1], a2 = p0[node * 3 + 2];
    for (; e + 2 <= en; e += 2) {
        int s0 = srcs[e] * 3, s1 = srcs[e + 1] * 3;
        float u0 = p0[s0], u1 = p0[s0 + 1], u2 = p0[s0 + 2];
        float w0 = p0[s1], w1 = p0[s1 + 1], w2 = p0[s1 + 2];
        a0 += u0 + w0; a1 += u1 + w1; a2 += u2 + w2;
    }
    for (; e < en; ++e) {
        int s = srcs[e] * 3;
        a0 += p0[s]; a1 += p0[s + 1]; a2 += p0[s + 2];
    }
    q4s[t] = make_float4(a0, a1, a2, dinv[node]);
    __syncthreads();
    int j = t & 31;
    int d0 = 2 * j, d1 = d0 + 1;
    float w00 = W1[d0], w10 = W1[64 + d0], w20 = W1[128 + d0], bb0 = b1[d0];
    float w01 = W1[d1], w11 = W1[64 + d1], w21 = W1[128 + d1], bb1 = b1[d1];
    size_t base = (size_t)blockIdx.x * 256 * 32;
    #pragma unroll 8
    for (int i = 0; i < 32; ++i) {
        int idx = t + 256 * i;
        float4 q = q4s[idx >> 5];
        float h0 = fmaf(q.w, fmaf(q.x, w00, fmaf(q.y, w10, q.z * w20)), bb0);
        float h1 = fmaf(q.w, fmaf(q.x, w01, fmaf(q.y, w11, q.z * w21)), bb1);
        p1h[base + idx] = __floats2half2_rn(q.w * fmaxf(h0, 0.f), q.w * fmaxf(h1, 0.f));
    }
}

// ---------------------------------------------------------------------------
// 64-dim aggregation, fp16 in / fp16 out: row = 128 B = 8 lanes x 16 B.
// 8-lane group grp takes edges e0+grp+8k (2-deep); fp32 accumulate;
// butterfly (^8,^16,^32); grp 0 packs to half2 and stores 16 B.
// ---------------------------------------------------------------------------
__global__ __launch_bounds__(256) void agg64_kernel(const int* __restrict__ beg,
                                                    const int* __restrict__ end,
                                                    const unsigned* __restrict__ srcs,
                                                    const __half2* __restrict__ g,
                                                    __half2* __restrict__ q1h) {
    int lane = threadIdx.x & 63;
    int node = (blockIdx.x * blockDim.x + threadIdx.x) >> 6;
    if (node >= NV) return;
    int grp = lane >> 3, sub = lane & 7;
    const uint4* base = (const uint4*)g;   // 8 uint4 per node row
    float a0 = 0.f, a1 = 0.f, a2 = 0.f, a3 = 0.f;
    float a4 = 0.f, a5 = 0.f, a6 = 0.f, a7 = 0.f;
#define UNPACK_ADD(v) do { float2 f_;                                         \
        f_ = __half22float2(*(const __half2*)&(v).x); a0 += f_.x; a1 += f_.y; \
        f_ = __half22float2(*(const __half2*)&(v).y); a2 += f_.x; a3 += f_.y; \
        f_ = __half22float2(*(const __half2*)&(v).z); a4 += f_.x; a5 += f_.y; \
        f_ = __half22float2(*(const __half2*)&(v).w); a6 += f_.x; a7 += f_.y; } while (0)
    if (grp == 0) {
        uint4 v = base[((size_t)node << 3) + sub];   // self loop
        UNPACK_ADD(v);
    }
    int e = beg[node] + grp, en = end[node];
    for (; e + 8 < en; e += 16) {
        uint4 v0 = base[((size_t)srcs[e] << 3) + sub];
        uint4 v1 = base[((size_t)srcs[e + 8] << 3) + sub];
        UNPACK_ADD(v0);
        UNPACK_ADD(v1);
    }
    if (e < en) {
        uint4 v = base[((size_t)srcs[e] << 3) + sub];
        UNPACK_ADD(v);
    }
#undef UNPACK_ADD
    #pragma unroll
    for (int m = 8; m <= 32; m <<= 1) {
        a0 += __shfl_xor(a0, m); a1 += __shfl_xor(a1, m);
        a2 += __shfl_xor(a2, m); a3 += __shfl_xor(a3, m);
        a4 += __shfl_xor(a4, m); a5 += __shfl_xor(a5, m);
        a6 += __shfl_xor(a6, m); a7 += __shfl_xor(a7, m);
    }
    if (grp == 0) {
        uint4 o;
        *(__half2*)&o.x = __floats2half2_rn(a0, a1);
        *(__half2*)&o.y = __floats2half2_rn(a2, a3);
        *(__half2*)&o.z = __floats2half2_rn(a4, a5);
        *(__half2*)&o.w = __floats2half2_rn(a6, a7);
        ((uint4*)q1h)[((size_t)node << 3) + sub] = o;
    }
}

// ---------------------------------------------------------------------------
// Fused layer-2 transform + partial pooling: 4x4 register-tiled GEMM,
// 0.125 LDS-fetch/FMA, fp16 q1 input (converted to fp32 in LDS staging).
// ---------------------------------------------------------------------------
__global__ __launch_bounds__(256) void trans2pool_kernel(const __half* __restrict__ q1h,
                                                         const float* __restrict__ dinv,
                                                         const float* __restrict__ b2,
                                                         const float* __restrict__ W2,
                                                         float* __restrict__ partials) {
    __shared__ float w2s[64 * 64];        // 16 KB, [k][d]
    __shared__ float rT[4][64 * RST];     // 20 KB, per-wave transposed rows [k][r]
    int t = threadIdx.x;
    int lane = t & 63, wvid = t >> 6;
    for (int i = t; i < 64 * 64; i += 256) w2s[i] = W2[i];

    int wid = blockIdx.x * 4 + wvid;
    int n0 = wid * RPW;
    float v[16];
    #pragma unroll
    for (int i = 0; i < 16; ++i)
        v[i] = __half2float(q1h[((size_t)(n0 + i) << 6) + lane]);
    float* rw = rT[wvid];
    #pragma unroll
    for (int r0 = 0; r0 < 16; r0 += 4)
        *(float4*)&rw[lane * RST + r0] = make_float4(v[r0], v[r0 + 1], v[r0 + 2], v[r0 + 3]);
    __syncthreads();

    int ri0 = (lane >> 4) * 4;            // row sub-tile: 0,4,8,12
    int c0 = (lane & 15) * 4;             // col sub-tile: 0..60
    float acc00 = 0.f, acc01 = 0.f, acc02 = 0.f, acc03 = 0.f;
    float acc10 = 0.f, acc11 = 0.f, acc12 = 0.f, acc13 = 0.f;
    float acc20 = 0.f, acc21 = 0.f, acc22 = 0.f, acc23 = 0.f;
    float acc30 = 0.f, acc31 = 0.f, acc32 = 0.f, acc33 = 0.f;
    #pragma unroll 2
    for (int k = 0; k < 64; ++k) {
        float4 w4 = *(const float4*)&w2s[k * 64 + c0];
        float4 r4 = *(const float4*)&rw[k * RST + ri0];
        acc00 = fmaf(r4.x, w4.x, acc00); acc01 = fmaf(r4.x, w4.y, acc01);
        acc02 = fmaf(r4.x, w4.z, acc02); acc03 = fmaf(r4.x, w4.w, acc03);
        acc10 = fmaf(r4.y, w4.x, acc10); acc11 = fmaf(r4.y, w4.y, acc11);
        acc12 = fmaf(r4.y, w4.z, acc12); acc13 = fmaf(r4.y, w4.w, acc13);
        acc20 = fmaf(r4.z, w4.x, acc20); acc21 = fmaf(r4.z, w4.y, acc21);
        acc22 = fmaf(r4.z, w4.z, acc22); acc23 = fmaf(r4.z, w4.w, acc23);
        acc30 = fmaf(r4.w, w4.x, acc30); acc31 = fmaf(r4.w, w4.y, acc31);
        acc32 = fmaf(r4.w, w4.z, acc32); acc33 = fmaf(r4.w, w4.w, acc33);
    }
    float4 bv = *(const float4*)&b2[c0];
    float d0 = dinv[n0 + ri0 + 0], d1 = dinv[n0 + ri0 + 1];
    float d2 = dinv[n0 + ri0 + 2], d3 = dinv[n0 + ri0 + 3];
    float s0 = fmaxf(fmaf(d0, acc00, bv.x), 0.f) + fmaxf(fmaf(d1, acc10, bv.x), 0.f)
             + fmaxf(fmaf(d2, acc20, bv.x), 0.f) + fmaxf(fmaf(d3, acc30, bv.x), 0.f);
    float s1 = fmaxf(fmaf(d0, acc01, bv.y), 0.f) + fmaxf(fmaf(d1, acc11, bv.y), 0.f)
             + fmaxf(fmaf(d2, acc21, bv.y), 0.f) + fmaxf(fmaf(d3, acc31, bv.y), 0.f);
    float s2 = fmaxf(fmaf(d0, acc02, bv.z), 0.f) + fmaxf(fmaf(d1, acc12, bv.z), 0.f)
             + fmaxf(fmaf(d2, acc22, bv.z), 0.f) + fmaxf(fmaf(d3, acc32, bv.z), 0.f);
    float s3 = fmaxf(fmaf(d0, acc03, bv.w), 0.f) + fmaxf(fmaf(d1, acc13, bv.w), 0.f)
             + fmaxf(fmaf(d2, acc23, bv.w), 0.f) + fmaxf(fmaf(d3, acc33, bv.w), 0.f);
    s0 += __shfl_xor(s0, 16); s1 += __shfl_xor(s1, 16);
    s2 += __shfl_xor(s2, 16); s3 += __shfl_xor(s3, 16);
    s0 += __shfl_xor(s0, 32); s1 += __shfl_xor(s1, 32);
    s2 += __shfl_xor(s2, 32); s3 += __shfl_xor(s3, 32);
    if (lane < 16)
        *(float4*)&partials[(size_t)wid * 64 + c0] = make_float4(s0, s1, s2, s3);
}

// Reduce WPG=125 partials per graph (4-way parallel); apply head.
__global__ __launch_bounds__(256) void pool_finish_kernel(const float* __restrict__ partials,
                                                          const float* __restrict__ Wh,
                                                          const float* __restrict__ bh,
                                                          float* __restrict__ out) {
    __shared__ float part[4][64];
    __shared__ float pooled[64];
    int b = blockIdx.x;
    int t = threadIdx.x;
    int d = t & 63, g = t >> 6;
    float s = 0.f;
    for (int c = g; c < WPG; c += 4)
        s += partials[((size_t)(b * WPG + c)) * 64 + d];
    part[g][d] = s;
    __syncthreads();
    if (t < 64)
        pooled[t] = (part[0][t] + part[1][t] + part[2][t] + part[3][t]) * (1.0f / NN);
    __syncthreads();
    if (t < 2) {
        float o = bh[t];
        #pragma unroll 16
        for (int k = 0; k < 64; ++k) o += pooled[k] * Wh[k * 2 + t];
        out[b * 2 + t] = o;
    }
}

extern "C" void kernel_launch(void* const* d_in, const int* in_sizes, int n_in,
                              void* d_out, int out_size, void* d_ws, size_t ws_size,
                              hipStream_t stream) {
    const float* x  = (const float*)d_in[0];
    const int*   ei = (const int*)d_in[1];
    const float* W1 = (const float*)d_in[2];
    const float* b1 = (const float*)d_in[3];
    const float* W2 = (const float*)d_in[4];
    const float* b2 = (const float*)d_in[5];
    const float* Wh = (const float*)d_in[6];
    const float* bh = (const float*)d_in[7];
    float* out = (float*)d_out;

    float* ws   = (float*)d_ws;
    float* bufA = ws;                          // NV*DD floats reserved (p1h: 8 MB)
    float* bufB = bufA + (size_t)NV * DD;      // NV*DD floats reserved (q1h: 8 MB)
    float* p0   = bufB + (size_t)NV * DD;      // NV*FF
    float* dinv = p0 + (size_t)NV * FF;        // NV
    float* partials = dinv + NV;               // NWAVES*64
    unsigned* parts = (unsigned*)(partials + (size_t)NWAVES * 64);  // KB*CAP
    int*   beg  = (int*)(parts + (size_t)KB * CAP);                 // NV
    int*   end  = beg + NV;                    // NV
    int*   gcur = end + NV;                    // KB
    __half2* p1h = (__half2*)bufA;             // NV*32 half2 (8 MB)
    __half2* q1h = (__half2*)bufB;             // NV*32 half2 (8 MB)

    // --- zero bucket cursors (async, capture-safe), then fat part+tmean ---
    hipMemsetAsync(gcur, 0, KB * sizeof(int), stream);
    part_tmean_kernel<<<NBLKA + TMB, 256, 0, stream>>>(ei, gcur, parts, x, p0);

    // --- per-bucket sort (+ dinv, + p0 scaling) ---
    bsort_kernel<<<KB, 256, 0, stream>>>(parts, gcur, beg, end, dinv, p0);

    // --- FUSED layer-1 aggregation + transform -> fp16 p1 ---
    agg3trans_kernel<<<NV / 256, 256, 0, stream>>>(beg, end, parts, p0, dinv, W1, b1, p1h);

    // --- Layer 2 aggregation (fp16 gather, fp32 accumulate, fp16 out) ---
    agg64_kernel<<<NV * 64 / 256, 256, 0, stream>>>(beg, end, parts, p1h, q1h);

    // --- Fused layer-2 transform + partial pool (4x4 register-tiled GEMM) ---
    trans2pool_kernel<<<NWAVES / 4, 256, 0, stream>>>((const __half*)q1h, dinv, b2, W2, partials);

    // --- Head ---
    pool_finish_kernel<<<BB, 256, 0, stream>>>(partials, Wh, bh, out);
}